// Round 2
// baseline (1214.606 us; speedup 1.0000x reference)
//
#include <hip/hip_runtime.h>
#include <math.h>

typedef unsigned int uint;
typedef unsigned short ushort;
typedef short bf16x8 __attribute__((ext_vector_type(8)));
typedef float f32x4 __attribute__((ext_vector_type(4)));

#define EPSV 1e-5f
#define SCALE 0.17677669529663687f   // 1/sqrt(32)

// param buffer offsets (bf16 elements) inside d_ws
#define OFF_WQKV 0
#define OFF_WOUT 196608
#define OFF_BQKV 262144
#define OFF_BOUT 262912
#define OFF_LNXW 263168
#define OFF_LNXB 263424
#define OFF_LNRW 263680
#define OFF_LNRB 263936

// dynamic LDS layout (bytes)
#define L_XN 0        // ushort[64][264]  xn -> q (in-place) -> ao
#define L_RN 33792    // ushort[64][264]  rn -> k (in-place)
#define L_VT 67584    // ushort[256][72]  vT[ch][tok]
#define L_P  104448   // ushort[4][64][72] per-wave P staging
#define LDS_TOTAL 141312

__device__ __forceinline__ float bf2f(ushort u) {
    union { float f; uint i; } z; z.i = ((uint)u) << 16; return z.f;
}
__device__ __forceinline__ ushort f2bf(float f) {
    union { float f; uint i; } z; z.f = f;
    uint i = z.i;
    return (ushort)((i + 0x7FFFu + ((i >> 16) & 1u)) >> 16);
}

// fp32 words have uniform bits14..7 (~17% in-range); packed-bf16 words have the
// low element's exponent there (~100% in-range for randn data).
__device__ __forceinline__ bool detect_f32(const uint* __restrict__ xw) {
    int cnt = 0;
    #pragma unroll
    for (int i = 0; i < 64; ++i) {
        uint e = (xw[i] >> 7) & 0xFFu;
        cnt += (e >= 0x60u && e <= 0x8Au) ? 1 : 0;
    }
    return cnt < 32;
}

// ---------------------------------------------------------------------------
// Param conversion: normalize all 8 weight/bias tensors into bf16 in d_ws.
// ---------------------------------------------------------------------------
__global__ __launch_bounds__(256) void kParams(
    const void* __restrict__ x,
    const void* __restrict__ lnxw, const void* __restrict__ lnxb,
    const void* __restrict__ lnrw, const void* __restrict__ lnrb,
    const void* __restrict__ wqkv, const void* __restrict__ bqkv,
    const void* __restrict__ wout, const void* __restrict__ bout,
    ushort* __restrict__ pb)
{
    const bool f32 = detect_f32((const uint*)x);
    const int blk = blockIdx.x, tid = threadIdx.x;
    const void* src; int si, doff;
    if (blk < 768)        { src = wqkv; si = blk * 256 + tid;          doff = OFF_WQKV; }
    else if (blk < 1024)  { src = wout; si = (blk - 768) * 256 + tid;  doff = OFF_WOUT; }
    else if (blk < 1027)  { src = bqkv; si = (blk - 1024) * 256 + tid; doff = OFF_BQKV; }
    else if (blk == 1027) { src = bout; si = tid; doff = OFF_BOUT; }
    else if (blk == 1028) { src = lnxw; si = tid; doff = OFF_LNXW; }
    else if (blk == 1029) { src = lnxb; si = tid; doff = OFF_LNXB; }
    else if (blk == 1030) { src = lnrw; si = tid; doff = OFF_LNRW; }
    else                  { src = lnrb; si = tid; doff = OFF_LNRB; }
    pb[doff + si] = f32 ? f2bf(((const float*)src)[si]) : ((const ushort*)src)[si];
}

// ---------------------------------------------------------------------------
// Fused per-window kernel: LN -> QKV -> attention -> out-proj -> scatter.
// 4 waves/block; wave owns token stripe [wave*16, wave*16+16) for GEMMs and
// heads {2*wave, 2*wave+1} for attention.
// ---------------------------------------------------------------------------
__global__ __launch_bounds__(256) void kMain(
    const void* __restrict__ xv, const void* __restrict__ rv,
    const ushort* __restrict__ pb, void* __restrict__ outv)
{
    extern __shared__ char smem[];
    ushort (*xn)[264]    = (ushort (*)[264])(smem + L_XN);
    ushort (*rn)[264]    = (ushort (*)[264])(smem + L_RN);
    ushort (*vT)[72]     = (ushort (*)[72])(smem + L_VT);
    ushort (*Pp)[64][72] = (ushort (*)[64][72])(smem + L_P);

    const bool f32 = detect_f32((const uint*)xv);
    const int w = blockIdx.x, b = w >> 8, hw = (w >> 4) & 15, ww = w & 15;
    const int tid = threadIdx.x;
    const int lane = tid & 63, wave = tid >> 6;
    const int col = lane & 15, quad = lane >> 4;

    // ---- Phase 1: LayerNorm into LDS (bf16). 4 threads per token row. ----
    {
        const int row = tid >> 2, l4 = tid & 3;
        const int pi = row >> 3, pj = row & 7;
        const size_t gidx = ((size_t)((b * 128 + hw * 8 + pi) * 128 + ww * 8 + pj)) * 256
                          + (size_t)(l4 * 64);
        #pragma unroll 1
        for (int t = 0; t < 2; ++t) {
            const void* src = t ? rv : xv;
            const ushort* lw = pb + (t ? OFF_LNRW : OFF_LNXW);
            const ushort* lb = pb + (t ? OFF_LNRB : OFF_LNXB);
            ushort (*dst)[264] = t ? rn : xn;

            float vals[64];
            if (f32) {
                const float4* g = (const float4*)((const float*)src + gidx);
                #pragma unroll
                for (int it = 0; it < 16; ++it) {
                    float4 q = g[it];
                    vals[it * 4 + 0] = q.x; vals[it * 4 + 1] = q.y;
                    vals[it * 4 + 2] = q.z; vals[it * 4 + 3] = q.w;
                }
            } else {
                const uint4* g = (const uint4*)((const ushort*)src + gidx);
                #pragma unroll
                for (int it = 0; it < 8; ++it) {
                    uint4 q = g[it];
                    uint u[4] = {q.x, q.y, q.z, q.w};
                    #pragma unroll
                    for (int e = 0; e < 4; ++e) {
                        vals[it * 8 + e * 2]     = bf2f((ushort)(u[e] & 0xffff));
                        vals[it * 8 + e * 2 + 1] = bf2f((ushort)(u[e] >> 16));
                    }
                }
            }
            float s0 = 0.f, s1 = 0.f;
            #pragma unroll
            for (int c = 0; c < 64; ++c) { s0 += vals[c]; s1 += vals[c] * vals[c]; }
            s0 += __shfl_xor(s0, 1); s1 += __shfl_xor(s1, 1);
            s0 += __shfl_xor(s0, 2); s1 += __shfl_xor(s1, 2);
            const float mean = s0 * (1.f / 256.f);
            const float var  = s1 * (1.f / 256.f) - mean * mean;
            const float rs   = rsqrtf(var + EPSV);

            #pragma unroll
            for (int c = 0; c < 64; c += 2) {
                const int ch = l4 * 64 + c;
                float a = (vals[c]     - mean) * rs * bf2f(lw[ch])     + bf2f(lb[ch]);
                float d = (vals[c + 1] - mean) * rs * bf2f(lw[ch + 1]) + bf2f(lb[ch + 1]);
                *(uint*)&dst[row][ch] = (uint)f2bf(a) | ((uint)f2bf(d) << 16);
            }
        }
    }
    __syncthreads();

    // ---- Phase 2: QKV GEMM. A-frags register-resident, then q/k in-place. ----
    {
        bf16x8 ax[8], ar[8];
        #pragma unroll
        for (int ks = 0; ks < 8; ++ks) {
            ax[ks] = *(const bf16x8*)&xn[wave * 16 + col][ks * 32 + quad * 8];
            ar[ks] = *(const bf16x8*)&rn[wave * 16 + col][ks * 32 + quad * 8];
        }
        const ushort* wq = pb + OFF_WQKV;
        #pragma unroll 1
        for (int seg = 0; seg < 3; ++seg) {
            const int sseg = (seg == 0) ? 2 : (seg == 1) ? 1 : 0;  // v, k, q
            const bf16x8* afr = (sseg == 0) ? ax : ar;
            #pragma unroll 4
            for (int ntl = 0; ntl < 16; ++ntl) {
                const int wrow = (sseg * 16 + ntl) * 16 + col;
                f32x4 acc = {0.f, 0.f, 0.f, 0.f};
                #pragma unroll
                for (int ks = 0; ks < 8; ++ks) {
                    bf16x8 bfr = *(const bf16x8*)(wq + wrow * 256 + ks * 32 + quad * 8);
                    acc = __builtin_amdgcn_mfma_f32_16x16x32_bf16(afr[ks], bfr, acc, 0, 0, 0);
                }
                const float bias = bf2f(pb[OFF_BQKV + wrow]);
                #pragma unroll
                for (int rg = 0; rg < 4; ++rg) {
                    const int trow = wave * 16 + quad * 4 + rg;
                    const float val = acc[rg] + bias;
                    if (sseg == 2)      vT[ntl * 16 + col][trow] = f2bf(val);
                    else if (sseg == 1) rn[trow][ntl * 16 + col] = f2bf(val);
                    else                xn[trow][ntl * 16 + col] = f2bf(val * SCALE);
                }
            }
        }
    }
    __syncthreads();

    // ---- Phase 3: attention, 2 heads per wave, ao overwrites q's band. ----
    #pragma unroll 1
    for (int hh = 0; hh < 2; ++hh) {
        const int head = wave * 2 + hh;
        bf16x8 qa[4], kb[4];
        #pragma unroll
        for (int mt = 0; mt < 4; ++mt)
            qa[mt] = *(const bf16x8*)&xn[mt * 16 + col][head * 32 + quad * 8];
        #pragma unroll
        for (int nt = 0; nt < 4; ++nt)
            kb[nt] = *(const bf16x8*)&rn[nt * 16 + col][head * 32 + quad * 8];

        f32x4 sc[4][4];
        #pragma unroll
        for (int mt = 0; mt < 4; ++mt)
            #pragma unroll
            for (int nt = 0; nt < 4; ++nt) {
                f32x4 z = {0.f, 0.f, 0.f, 0.f};
                sc[mt][nt] = __builtin_amdgcn_mfma_f32_16x16x32_bf16(qa[mt], kb[nt], z, 0, 0, 0);
            }

        #pragma unroll
        for (int mt = 0; mt < 4; ++mt) {
            #pragma unroll
            for (int rg = 0; rg < 4; ++rg) {
                float m = fmaxf(fmaxf(sc[mt][0][rg], sc[mt][1][rg]),
                                fmaxf(sc[mt][2][rg], sc[mt][3][rg]));
                m = fmaxf(m, __shfl_xor(m, 1));
                m = fmaxf(m, __shfl_xor(m, 2));
                m = fmaxf(m, __shfl_xor(m, 4));
                m = fmaxf(m, __shfl_xor(m, 8));
                float p0 = __expf(sc[mt][0][rg] - m);
                float p1 = __expf(sc[mt][1][rg] - m);
                float p2 = __expf(sc[mt][2][rg] - m);
                float p3 = __expf(sc[mt][3][rg] - m);
                float s = p0 + p1 + p2 + p3;
                s += __shfl_xor(s, 1);
                s += __shfl_xor(s, 2);
                s += __shfl_xor(s, 4);
                s += __shfl_xor(s, 8);
                const float inv = 1.f / s;
                sc[mt][0][rg] = p0 * inv; sc[mt][1][rg] = p1 * inv;
                sc[mt][2][rg] = p2 * inv; sc[mt][3][rg] = p3 * inv;
            }
        }

        #pragma unroll
        for (int mt = 0; mt < 4; ++mt)
            #pragma unroll
            for (int nt = 0; nt < 4; ++nt)
                #pragma unroll
                for (int rg = 0; rg < 4; ++rg)
                    Pp[wave][mt * 16 + quad * 4 + rg][nt * 16 + col] = f2bf(sc[mt][nt][rg]);

        #pragma unroll
        for (int mt = 0; mt < 4; ++mt) {
            #pragma unroll
            for (int n2 = 0; n2 < 2; ++n2) {
                f32x4 acc = {0.f, 0.f, 0.f, 0.f};
                #pragma unroll
                for (int kt = 0; kt < 2; ++kt) {
                    bf16x8 a  = *(const bf16x8*)&Pp[wave][mt * 16 + col][kt * 32 + quad * 8];
                    bf16x8 bv = *(const bf16x8*)&vT[head * 32 + n2 * 16 + col][kt * 32 + quad * 8];
                    acc = __builtin_amdgcn_mfma_f32_16x16x32_bf16(a, bv, acc, 0, 0, 0);
                }
                #pragma unroll
                for (int rg = 0; rg < 4; ++rg)
                    xn[mt * 16 + quad * 4 + rg][head * 32 + n2 * 16 + col] = f2bf(acc[rg]);
            }
        }
    }
    __syncthreads();

    // ---- Phase 4: out-projection + scatter (dtype-branched store). ----
    {
        bf16x8 af[8];
        #pragma unroll
        for (int ks = 0; ks < 8; ++ks)
            af[ks] = *(const bf16x8*)&xn[wave * 16 + col][ks * 32 + quad * 8];
        const ushort* wo = pb + OFF_WOUT;
        #pragma unroll 4
        for (int ntl = 0; ntl < 16; ++ntl) {
            const int orow = ntl * 16 + col;
            f32x4 acc = {0.f, 0.f, 0.f, 0.f};
            #pragma unroll
            for (int ks = 0; ks < 8; ++ks) {
                bf16x8 bfr = *(const bf16x8*)(wo + orow * 256 + ks * 32 + quad * 8);
                acc = __builtin_amdgcn_mfma_f32_16x16x32_bf16(af[ks], bfr, acc, 0, 0, 0);
            }
            const float bias = bf2f(pb[OFF_BOUT + orow]);
            #pragma unroll
            for (int rg = 0; rg < 4; ++rg) {
                const int t = wave * 16 + quad * 4 + rg;
                const int pi = t >> 3, pj = t & 7;
                const size_t gi = ((size_t)((b * 128 + hw * 8 + pi) * 128 + ww * 8 + pj)) * 256
                                + (size_t)orow;
                const float val = acc[rg] + bias;
                if (f32) ((float*)outv)[gi] = val;
                else     ((ushort*)outv)[gi] = f2bf(val);
            }
        }
    }
}

// ---------------------------------------------------------------------------
extern "C" void kernel_launch(void* const* d_in, const int* in_sizes, int n_in,
                              void* d_out, int out_size, void* d_ws, size_t ws_size,
                              hipStream_t stream)
{
    const void* x    = d_in[0];
    const void* r    = d_in[1];
    const void* lnxw = d_in[2];
    const void* lnxb = d_in[3];
    const void* lnrw = d_in[4];
    const void* lnrb = d_in[5];
    const void* wqkv = d_in[6];
    const void* bqkv = d_in[7];
    const void* wout = d_in[8];
    const void* bout = d_in[9];

    ushort* pb = (ushort*)d_ws;   // 264192 bf16 elements = 516 KB

    kParams<<<1032, 256, 0, stream>>>(x, lnxw, lnxb, lnrw, lnrb,
                                      wqkv, bqkv, wout, bout, pb);

    (void)hipFuncSetAttribute((const void*)kMain,
                              hipFuncAttributeMaxDynamicSharedMemorySize, LDS_TOTAL);
    kMain<<<2048, 256, LDS_TOTAL, stream>>>(x, r, pb, d_out);
}

// Round 3
// 791.539 us; speedup vs baseline: 1.5345x; 1.5345x over previous
//
#include <hip/hip_runtime.h>
#include <math.h>

typedef unsigned int uint;
typedef unsigned short ushort;
typedef short bf16x8 __attribute__((ext_vector_type(8)));
typedef float f32x4 __attribute__((ext_vector_type(4)));

#define EPSV 1e-5f
#define SCALE 0.17677669529663687f   // 1/sqrt(32)

// param buffer offsets (bf16 elements) inside d_ws
#define OFF_WQKV 0
#define OFF_WOUT 196608
#define OFF_BQKV 262144
#define OFF_BOUT 262912
#define OFF_LNXW 263168
#define OFF_LNXB 263424
#define OFF_LNRW 263680
#define OFF_LNRB 263936

// dynamic LDS layout (bytes): k-buffer, vT (shared w/ LN-r staging & out staging),
// per-wave P/transpose scratch. 79872 B -> 2 blocks/CU.
#define L_RN 0        // ushort[64][264]   LN(x) -> k (in place)
#define L_VT 33792    // ushort[256][72]   LN(r) staging -> vT[ch][tok] -> out staging
#define L_P  70656    // ushort[4][16][72] per-wave P + q/ao transpose scratch
#define LDS_TOTAL 79872

__device__ __forceinline__ float bf2f(ushort u) {
    union { float f; uint i; } z; z.i = ((uint)u) << 16; return z.f;
}
__device__ __forceinline__ ushort f2bf(float f) {
    union { float f; uint i; } z; z.f = f;
    uint i = z.i;
    return (ushort)((i + 0x7FFFu + ((i >> 16) & 1u)) >> 16);
}
__device__ __forceinline__ uint pack2(float a, float b) {
    return (uint)f2bf(a) | ((uint)f2bf(b) << 16);
}

// fp32 words have uniform bits14..7; packed-bf16 words carry the low element's
// exponent there (concentrated for randn data).
__device__ __forceinline__ bool detect_f32(const uint* __restrict__ xw) {
    int cnt = 0;
    #pragma unroll
    for (int i = 0; i < 64; ++i) {
        uint e = (xw[i] >> 7) & 0xFFu;
        cnt += (e >= 0x60u && e <= 0x8Au) ? 1 : 0;
    }
    return cnt < 32;
}

// ---------------------------------------------------------------------------
// Param conversion: normalize all 8 weight/bias tensors into bf16 in d_ws.
// ---------------------------------------------------------------------------
__global__ __launch_bounds__(256) void kParams(
    const void* __restrict__ x,
    const void* __restrict__ lnxw, const void* __restrict__ lnxb,
    const void* __restrict__ lnrw, const void* __restrict__ lnrb,
    const void* __restrict__ wqkv, const void* __restrict__ bqkv,
    const void* __restrict__ wout, const void* __restrict__ bout,
    ushort* __restrict__ pb)
{
    const bool f32 = detect_f32((const uint*)x);
    const int blk = blockIdx.x, tid = threadIdx.x;
    const void* src; int si, doff;
    if (blk < 768)        { src = wqkv; si = blk * 256 + tid;          doff = OFF_WQKV; }
    else if (blk < 1024)  { src = wout; si = (blk - 768) * 256 + tid;  doff = OFF_WOUT; }
    else if (blk < 1027)  { src = bqkv; si = (blk - 1024) * 256 + tid; doff = OFF_BQKV; }
    else if (blk == 1027) { src = bout; si = tid; doff = OFF_BOUT; }
    else if (blk == 1028) { src = lnxw; si = tid; doff = OFF_LNXW; }
    else if (blk == 1029) { src = lnxb; si = tid; doff = OFF_LNXB; }
    else if (blk == 1030) { src = lnrw; si = tid; doff = OFF_LNRW; }
    else                  { src = lnrb; si = tid; doff = OFF_LNRB; }
    pb[doff + si] = f32 ? f2bf(((const float*)src)[si]) : ((const ushort*)src)[si];
}

// ---------------------------------------------------------------------------
// Fused per-window kernel. Wave owns token stripe [wave*16, +16).
// q and ao live in packed C-layout VGPRs; LDS holds only k, vT, P-scratch.
// ---------------------------------------------------------------------------
__global__ __launch_bounds__(256, 2) void kMain(
    const void* __restrict__ xv, const void* __restrict__ rv,
    const ushort* __restrict__ pb, void* __restrict__ outv)
{
    extern __shared__ char smem[];
    ushort (*rn)[264]     = (ushort (*)[264])(smem + L_RN);   // LN(x) -> k
    ushort (*rstage)[264] = (ushort (*)[264])(smem + L_VT);   // LN(r) staging
    ushort (*vT)[72]      = (ushort (*)[72])(smem + L_VT);    // v transposed
    ushort (*vo)[264]     = (ushort (*)[264])(smem + L_VT);   // out staging

    const bool f32 = detect_f32((const uint*)xv);
    const int w = blockIdx.x, b = w >> 8, hw = (w >> 4) & 15, ww = w & 15;
    const int tid = threadIdx.x;
    const int lane = tid & 63, wave = tid >> 6;
    const int col = lane & 15, quad = lane >> 4;
    ushort (*Pw)[72] = (ushort (*)[72])(smem + L_P + wave * 2304);

    // ---- Phase 1: LayerNorm both tensors into LDS. 4 threads/token. ----
    {
        const int row = tid >> 2, l4 = tid & 3;
        const int pi = row >> 3, pj = row & 7;
        const size_t gidx = ((size_t)((b * 128 + hw * 8 + pi) * 128 + ww * 8 + pj)) * 256
                          + (size_t)(l4 * 64);
        #pragma unroll 1
        for (int t = 0; t < 2; ++t) {
            const void* src = t ? rv : xv;
            const ushort* lw = pb + (t ? OFF_LNRW : OFF_LNXW);
            const ushort* lb = pb + (t ? OFF_LNRB : OFF_LNXB);
            ushort (*dst)[264] = t ? rstage : rn;

            float vals[64];
            if (f32) {
                const float4* g = (const float4*)((const float*)src + gidx);
                #pragma unroll
                for (int it = 0; it < 16; ++it) {
                    float4 q = g[it];
                    vals[it * 4 + 0] = q.x; vals[it * 4 + 1] = q.y;
                    vals[it * 4 + 2] = q.z; vals[it * 4 + 3] = q.w;
                }
            } else {
                const uint4* g = (const uint4*)((const ushort*)src + gidx);
                #pragma unroll
                for (int it = 0; it < 8; ++it) {
                    uint4 q = g[it];
                    uint u[4] = {q.x, q.y, q.z, q.w};
                    #pragma unroll
                    for (int e = 0; e < 4; ++e) {
                        vals[it * 8 + e * 2]     = bf2f((ushort)(u[e] & 0xffff));
                        vals[it * 8 + e * 2 + 1] = bf2f((ushort)(u[e] >> 16));
                    }
                }
            }
            float s0 = 0.f, s1 = 0.f;
            #pragma unroll
            for (int c = 0; c < 64; ++c) { s0 += vals[c]; s1 += vals[c] * vals[c]; }
            s0 += __shfl_xor(s0, 1); s1 += __shfl_xor(s1, 1);
            s0 += __shfl_xor(s0, 2); s1 += __shfl_xor(s1, 2);
            const float mean = s0 * (1.f / 256.f);
            const float var  = s1 * (1.f / 256.f) - mean * mean;
            const float rs   = rsqrtf(var + EPSV);
            #pragma unroll
            for (int c = 0; c < 64; c += 2) {
                const int ch = l4 * 64 + c;
                float a = (vals[c]     - mean) * rs * bf2f(lw[ch])     + bf2f(lb[ch]);
                float d = (vals[c + 1] - mean) * rs * bf2f(lw[ch + 1]) + bf2f(lb[ch + 1]);
                *(uint*)&dst[row][ch] = (uint)f2bf(a) | ((uint)f2bf(d) << 16);
            }
        }
    }
    __syncthreads();

    // ---- Phase 1b: A-fragments for both tensors into registers ----
    bf16x8 ax[8], ar[8];
    #pragma unroll
    for (int ks = 0; ks < 8; ++ks) {
        ax[ks] = *(const bf16x8*)&rn[wave * 16 + col][ks * 32 + quad * 8];
        ar[ks] = *(const bf16x8*)&rstage[wave * 16 + col][ks * 32 + quad * 8];
    }
    __syncthreads();

    // ---- Phase 2: QKV. q -> regs (packed C-layout), k -> rn, v -> vT ----
    uint qpk[16][2];
    {
        const ushort* wq = pb + OFF_WQKV;
        // q (fully unrolled: qpk must stay in registers)
        #pragma unroll
        for (int ntl = 0; ntl < 16; ++ntl) {
            const int wrow = ntl * 16 + col;
            const bf16x8* bp = (const bf16x8*)(wq + (size_t)wrow * 256 + quad * 8);
            bf16x8 bb[8];
            #pragma unroll
            for (int ks = 0; ks < 8; ++ks) bb[ks] = bp[ks * 4];
            f32x4 acc = {0.f, 0.f, 0.f, 0.f};
            #pragma unroll
            for (int ks = 0; ks < 8; ++ks)
                acc = __builtin_amdgcn_mfma_f32_16x16x32_bf16(ax[ks], bb[ks], acc, 0, 0, 0);
            const float bias = bf2f(pb[OFF_BQKV + wrow]);
            qpk[ntl][0] = pack2((acc[0] + bias) * SCALE, (acc[1] + bias) * SCALE);
            qpk[ntl][1] = pack2((acc[2] + bias) * SCALE, (acc[3] + bias) * SCALE);
        }
        // k -> rn stripe (in place over LN-x; ax/ar already in regs)
        #pragma unroll 2
        for (int ntl = 0; ntl < 16; ++ntl) {
            const int wrow = 256 + ntl * 16 + col;
            const bf16x8* bp = (const bf16x8*)(wq + (size_t)wrow * 256 + quad * 8);
            bf16x8 bb[8];
            #pragma unroll
            for (int ks = 0; ks < 8; ++ks) bb[ks] = bp[ks * 4];
            f32x4 acc = {0.f, 0.f, 0.f, 0.f};
            #pragma unroll
            for (int ks = 0; ks < 8; ++ks)
                acc = __builtin_amdgcn_mfma_f32_16x16x32_bf16(ar[ks], bb[ks], acc, 0, 0, 0);
            const float bias = bf2f(pb[OFF_BQKV + wrow]);
            #pragma unroll
            for (int rg = 0; rg < 4; ++rg)
                rn[wave * 16 + quad * 4 + rg][ntl * 16 + col] = f2bf(acc[rg] + bias);
        }
        // v -> vT[ch][tok] (overwrites rstage; b64 packed along tokens)
        #pragma unroll 2
        for (int ntl = 0; ntl < 16; ++ntl) {
            const int wrow = 512 + ntl * 16 + col;
            const bf16x8* bp = (const bf16x8*)(wq + (size_t)wrow * 256 + quad * 8);
            bf16x8 bb[8];
            #pragma unroll
            for (int ks = 0; ks < 8; ++ks) bb[ks] = bp[ks * 4];
            f32x4 acc = {0.f, 0.f, 0.f, 0.f};
            #pragma unroll
            for (int ks = 0; ks < 8; ++ks)
                acc = __builtin_amdgcn_mfma_f32_16x16x32_bf16(ar[ks], bb[ks], acc, 0, 0, 0);
            const float bias = bf2f(pb[OFF_BQKV + wrow]);
            uint2 pv;
            pv.x = pack2(acc[0] + bias, acc[1] + bias);
            pv.y = pack2(acc[2] + bias, acc[3] + bias);
            *(uint2*)&vT[ntl * 16 + col][wave * 16 + quad * 4] = pv;
        }
    }
    __syncthreads();

    // ---- Phase 3: attention, m-stripe split; loop all 8 heads (K=32 MFMA) ----
    uint aopk[16][2];
    #pragma unroll
    for (int h = 0; h < 8; ++h) {
        // q C-layout -> A-layout via per-wave scratch (aliases P band)
        #pragma unroll
        for (int tt = 0; tt < 2; ++tt) {
            const uint lo = qpk[2 * h + tt][0], hi = qpk[2 * h + tt][1];
            Pw[quad * 4 + 0][tt * 16 + col] = (ushort)(lo & 0xffff);
            Pw[quad * 4 + 1][tt * 16 + col] = (ushort)(lo >> 16);
            Pw[quad * 4 + 2][tt * 16 + col] = (ushort)(hi & 0xffff);
            Pw[quad * 4 + 3][tt * 16 + col] = (ushort)(hi >> 16);
        }
        const bf16x8 qa = *(const bf16x8*)&Pw[col][quad * 8];
        f32x4 s[4];
        #pragma unroll
        for (int nt = 0; nt < 4; ++nt) {
            const bf16x8 kb = *(const bf16x8*)&rn[nt * 16 + col][h * 32 + quad * 8];
            f32x4 z = {0.f, 0.f, 0.f, 0.f};
            s[nt] = __builtin_amdgcn_mfma_f32_16x16x32_bf16(qa, kb, z, 0, 0, 0);
        }
        #pragma unroll
        for (int rg = 0; rg < 4; ++rg) {
            float m = fmaxf(fmaxf(s[0][rg], s[1][rg]), fmaxf(s[2][rg], s[3][rg]));
            m = fmaxf(m, __shfl_xor(m, 1));
            m = fmaxf(m, __shfl_xor(m, 2));
            m = fmaxf(m, __shfl_xor(m, 4));
            m = fmaxf(m, __shfl_xor(m, 8));
            float p0 = __expf(s[0][rg] - m);
            float p1 = __expf(s[1][rg] - m);
            float p2 = __expf(s[2][rg] - m);
            float p3 = __expf(s[3][rg] - m);
            float sm = p0 + p1 + p2 + p3;
            sm += __shfl_xor(sm, 1);
            sm += __shfl_xor(sm, 2);
            sm += __shfl_xor(sm, 4);
            sm += __shfl_xor(sm, 8);
            const float inv = 1.f / sm;
            s[0][rg] = p0 * inv; s[1][rg] = p1 * inv;
            s[2][rg] = p2 * inv; s[3][rg] = p3 * inv;
        }
        #pragma unroll
        for (int nt = 0; nt < 4; ++nt)
            #pragma unroll
            for (int rg = 0; rg < 4; ++rg)
                Pw[quad * 4 + rg][nt * 16 + col] = f2bf(s[nt][rg]);
        const bf16x8 pa0 = *(const bf16x8*)&Pw[col][quad * 8];
        const bf16x8 pa1 = *(const bf16x8*)&Pw[col][32 + quad * 8];
        #pragma unroll
        for (int n2 = 0; n2 < 2; ++n2) {
            const bf16x8 bv0 = *(const bf16x8*)&vT[h * 32 + n2 * 16 + col][quad * 8];
            const bf16x8 bv1 = *(const bf16x8*)&vT[h * 32 + n2 * 16 + col][32 + quad * 8];
            f32x4 acc = {0.f, 0.f, 0.f, 0.f};
            acc = __builtin_amdgcn_mfma_f32_16x16x32_bf16(pa0, bv0, acc, 0, 0, 0);
            acc = __builtin_amdgcn_mfma_f32_16x16x32_bf16(pa1, bv1, acc, 0, 0, 0);
            aopk[2 * h + n2][0] = pack2(acc[0], acc[1]);
            aopk[2 * h + n2][1] = pack2(acc[2], acc[3]);
        }
    }
    __syncthreads();   // rn & vT free for reuse

    // ---- Phase 4: out-projection + coalesced store ----
    {
        // ao C-layout -> rn band (wave-local) -> A-frags
        #pragma unroll
        for (int t = 0; t < 16; ++t) {
            const uint lo = aopk[t][0], hi = aopk[t][1];
            rn[wave * 16 + quad * 4 + 0][t * 16 + col] = (ushort)(lo & 0xffff);
            rn[wave * 16 + quad * 4 + 1][t * 16 + col] = (ushort)(lo >> 16);
            rn[wave * 16 + quad * 4 + 2][t * 16 + col] = (ushort)(hi & 0xffff);
            rn[wave * 16 + quad * 4 + 3][t * 16 + col] = (ushort)(hi >> 16);
        }
        bf16x8 af[8];
        #pragma unroll
        for (int ks = 0; ks < 8; ++ks)
            af[ks] = *(const bf16x8*)&rn[wave * 16 + col][ks * 32 + quad * 8];

        const ushort* wo = pb + OFF_WOUT;
        #pragma unroll 2
        for (int ntl = 0; ntl < 16; ++ntl) {
            const int orow = ntl * 16 + col;
            const bf16x8* bp = (const bf16x8*)(wo + (size_t)orow * 256 + quad * 8);
            bf16x8 bb[8];
            #pragma unroll
            for (int ks = 0; ks < 8; ++ks) bb[ks] = bp[ks * 4];
            f32x4 acc = {0.f, 0.f, 0.f, 0.f};
            #pragma unroll
            for (int ks = 0; ks < 8; ++ks)
                acc = __builtin_amdgcn_mfma_f32_16x16x32_bf16(af[ks], bb[ks], acc, 0, 0, 0);
            const float bias = bf2f(pb[OFF_BOUT + orow]);
            if (!f32) {
                #pragma unroll
                for (int rg = 0; rg < 4; ++rg)
                    vo[wave * 16 + quad * 4 + rg][orow] = f2bf(acc[rg] + bias);
            } else {
                #pragma unroll
                for (int rg = 0; rg < 4; ++rg) {
                    const int t = wave * 16 + quad * 4 + rg;
                    const size_t gi = ((size_t)((b * 128 + hw * 8 + (t >> 3)) * 128
                                      + ww * 8 + (t & 7))) * 256 + (size_t)orow;
                    ((float*)outv)[gi] = acc[rg] + bias;
                }
            }
        }
        if (!f32) {
            // wave-local coalesced dump: 16 rows x 512B per wave
            const int row = wave * 16 + (lane >> 2), l4 = lane & 3;
            const size_t gbase = ((size_t)((b * 128 + hw * 8 + (row >> 3)) * 128
                                 + ww * 8 + (row & 7))) * 256 + (size_t)(l4 * 64);
            #pragma unroll
            for (int e = 0; e < 8; ++e) {
                uint4 vvv = *(const uint4*)&vo[row][l4 * 64 + e * 8];
                *(uint4*)((ushort*)outv + gbase + e * 8) = vvv;
            }
        }
    }
}

// ---------------------------------------------------------------------------
extern "C" void kernel_launch(void* const* d_in, const int* in_sizes, int n_in,
                              void* d_out, int out_size, void* d_ws, size_t ws_size,
                              hipStream_t stream)
{
    const void* x    = d_in[0];
    const void* r    = d_in[1];
    const void* lnxw = d_in[2];
    const void* lnxb = d_in[3];
    const void* lnrw = d_in[4];
    const void* lnrb = d_in[5];
    const void* wqkv = d_in[6];
    const void* bqkv = d_in[7];
    const void* wout = d_in[8];
    const void* bout = d_in[9];

    ushort* pb = (ushort*)d_ws;   // 264192 bf16 elements = 516 KB

    kParams<<<1032, 256, 0, stream>>>(x, lnxw, lnxb, lnrw, lnrb,
                                      wqkv, bqkv, wout, bout, pb);

    (void)hipFuncSetAttribute((const void*)kMain,
                              hipFuncAttributeMaxDynamicSharedMemorySize, LDS_TOTAL);
    kMain<<<2048, 256, LDS_TOTAL, stream>>>(x, r, pb, d_out);
}